// Round 1
// baseline (384.347 us; speedup 1.0000x reference)
//
#include <hip/hip_runtime.h>
#include <hip/hip_fp16.h>

#define T_TOTAL 262144
#define DD 128
#define HH 256
#define CHUNKS 1024
#define CHUNK_L (T_TOTAL / CHUNKS)   // 256
#define BURN 64
#define TILE 32

typedef _Float16 half2v __attribute__((ext_vector_type(2)));

__device__ __forceinline__ float dot2f(half2v a, half2v b, float c) {
#if __has_builtin(__builtin_amdgcn_fdot2)
    return __builtin_amdgcn_fdot2(a, b, c, false);
#else
    return c + (float)a[0] * (float)b[0] + (float)a[1] * (float)b[1];
#endif
}

__global__ __launch_bounds__(256, 4)
void rec_kernel(const float* __restrict__ X, const float* __restrict__ W1,
                const float* __restrict__ b1, const float* __restrict__ W2,
                const float* __restrict__ b2, float* __restrict__ out)
{
    const int c    = blockIdx.x;
    const int j    = threadIdx.x;    // 0..255, owns h_j
    const int lane = j & 63;
    const int wid  = j >> 6;

    __shared__ half2v xs[TILE][DD / 2];   // 32 rows x 64 half2 = 8 KB
    __shared__ float  partials[4];
    __shared__ float  zshare;

    // ---- load W1 row j (x-part) into registers as f16 pairs ----
    half2v w[DD / 2];
    const float* w1row = W1 + j * (DD + 1);
    #pragma unroll
    for (int k = 0; k < DD / 2; ++k) {
        half2v v;
        v[0] = (_Float16)w1row[2 * k];
        v[1] = (_Float16)w1row[2 * k + 1];
        w[k] = v;
    }
    const float wz  = w1row[DD];   // z-column, fp32
    const float bj  = b1[j];
    const float w2j = W2[j];
    const float b2s = b2[0];

    const int s0          = (c == 0) ? 0 : c * CHUNK_L - BURN;  // z_{s0} := 0
    const int t_end       = min((c + 1) * CHUNK_L, T_TOTAL - 1);
    const int write_start = c * CHUNK_L + 1;
    const int nsteps      = t_end - s0;          // t = s0+1 .. t_end
    const int ntiles      = (nsteps + TILE - 1) / TILE;

    if (c == 0 && j == 0) out[0] = 0.0f;

    float z = 0.0f;
    int   t = s0 + 1;

    for (int tile = 0; tile < ntiles; ++tile) {
        __syncthreads();   // previous tile fully consumed
        {
            // stage 32 x-rows: 4096 floats, 16 per thread
            const int r  = j >> 3;          // 0..31
            const int c0 = (j & 7) * 16;    // 0..112
            const float* src = X + (long long)(s0 + tile * TILE + r) * DD + c0;
            float4 f0 = *(const float4*)(src + 0);
            float4 f1 = *(const float4*)(src + 4);
            float4 f2 = *(const float4*)(src + 8);
            float4 f3 = *(const float4*)(src + 12);
            half2v* dst = &xs[r][c0 / 2];
            dst[0] = half2v{(_Float16)f0.x, (_Float16)f0.y};
            dst[1] = half2v{(_Float16)f0.z, (_Float16)f0.w};
            dst[2] = half2v{(_Float16)f1.x, (_Float16)f1.y};
            dst[3] = half2v{(_Float16)f1.z, (_Float16)f1.w};
            dst[4] = half2v{(_Float16)f2.x, (_Float16)f2.y};
            dst[5] = half2v{(_Float16)f2.z, (_Float16)f2.w};
            dst[6] = half2v{(_Float16)f3.x, (_Float16)f3.y};
            dst[7] = half2v{(_Float16)f3.z, (_Float16)f3.w};
        }
        __syncthreads();

        const int steps_this = min(TILE, t_end - (s0 + tile * TILE));
        for (int s = 0; s < steps_this; ++s, ++t) {
            const half2v* xr = xs[s];
            float acc0 = 0.f, acc1 = 0.f, acc2 = 0.f, acc3 = 0.f;
            #pragma unroll
            for (int k = 0; k < DD / 2; k += 4) {
                acc0 = dot2f(w[k + 0], xr[k + 0], acc0);
                acc1 = dot2f(w[k + 1], xr[k + 1], acc1);
                acc2 = dot2f(w[k + 2], xr[k + 2], acc2);
                acc3 = dot2f(w[k + 3], xr[k + 3], acc3);
            }
            const float a   = (acc0 + acc1) + (acc2 + acc3);
            const float pre = a + wz * z + bj;
            const float hj  = tanhf(pre);
            float p = w2j * hj;
            // 64-lane butterfly reduce
            #pragma unroll
            for (int m = 32; m > 0; m >>= 1) p += __shfl_xor(p, m, 64);
            if (lane == 0) partials[wid] = p;
            __syncthreads();
            if (j == 0) {
                const float u  = (partials[0] + partials[1]) +
                                 (partials[2] + partials[3]) + b2s;
                const float zn = tanhf(u);
                zshare = zn;
                if (t >= write_start) out[t] = zn;
            }
            __syncthreads();
            z = zshare;
        }
    }
}

extern "C" void kernel_launch(void* const* d_in, const int* in_sizes, int n_in,
                              void* d_out, int out_size, void* d_ws, size_t ws_size,
                              hipStream_t stream) {
    const float* X  = (const float*)d_in[0];
    const float* W1 = (const float*)d_in[1];
    const float* b1 = (const float*)d_in[2];
    const float* W2 = (const float*)d_in[3];
    const float* b2 = (const float*)d_in[4];
    float* out = (float*)d_out;
    (void)in_sizes; (void)n_in; (void)out_size; (void)d_ws; (void)ws_size;

    rec_kernel<<<CHUNKS, HH, 0, stream>>>(X, W1, b1, W2, b2, out);
}

// Round 2
// 379.155 us; speedup vs baseline: 1.0137x; 1.0137x over previous
//
#include <hip/hip_runtime.h>
#include <hip/hip_fp16.h>

#define T_TOTAL 262144
#define DD 128
#define HH 256
#define CHUNKS 512
#define CHUNK_L (T_TOTAL / CHUNKS)   // 512
#define BURN 32
#define TILE 16
#define NTHREADS 320                  // 4 producer waves + 1 consumer wave

typedef _Float16 half2v __attribute__((ext_vector_type(2)));

__device__ __forceinline__ float dot2f(half2v a, half2v b, float c) {
    return __builtin_amdgcn_fdot2(a, b, c, false);
}

// tanh(x) = 1 - 2/(exp(2x)+1); v_exp/v_rcp saturate correctly at +-inf
__device__ __forceinline__ float fast_tanh(float x) {
    float e = __expf(2.0f * x);
#if __has_builtin(__builtin_amdgcn_rcpf)
    float r = __builtin_amdgcn_rcpf(e + 1.0f);
#else
    float r = 1.0f / (e + 1.0f);
#endif
    return 1.0f - 2.0f * r;
}

template <int CTRL>
__device__ __forceinline__ float dpp_add(float x) {
    int t = __builtin_amdgcn_update_dpp(0, __float_as_int(x), CTRL, 0xf, 0xf, true);
    return x + __int_as_float(t);
}

// full wave64 sum -> result valid in lane 63
__device__ __forceinline__ float wave64_sum_lane63(float p) {
    p = dpp_add<0x111>(p);   // row_shr:1
    p = dpp_add<0x112>(p);   // row_shr:2
    p = dpp_add<0x114>(p);   // row_shr:4
    p = dpp_add<0x118>(p);   // row_shr:8
    p = dpp_add<0x142>(p);   // row_bcast:15
    p = dpp_add<0x143>(p);   // row_bcast:31
    return p;
}

__global__ __launch_bounds__(NTHREADS, 2)
void rec_kernel(const float* __restrict__ X, const float* __restrict__ W1,
                const float* __restrict__ b1, const float* __restrict__ W2,
                const float* __restrict__ b2, float* __restrict__ out)
{
    const int c   = blockIdx.x;
    const int tid = threadIdx.x;

    __shared__ float  As[2][TILE][HH];       // 32 KB, A[s][j] = W1x.x_s + b1_j
    __shared__ half2v xs[2][TILE][DD / 2];   // 8 KB, f16 x tiles

    const int s0     = (c == 0) ? 0 : c * CHUNK_L - BURN;
    const int t_end  = min((c + 1) * CHUNK_L, T_TOTAL - 1);
    const int nsteps = t_end - s0;                       // t = s0+1 .. t_end
    const int ntiles = (nsteps + TILE - 1) / TILE;
    const int write_start = c * CHUNK_L + 1;

    if (c == 0 && tid == 0) out[0] = 0.0f;

    const bool is_consumer = (tid >= 256);
    const int  lane = tid & 63;

    // ---------------- producer state: W1 x-row in VGPRs (f16) ----------------
    half2v w[DD / 2];
    float  bj = 0.0f;
    if (!is_consumer) {
        const float* w1row = W1 + tid * (DD + 1);
        #pragma unroll
        for (int k = 0; k < DD / 2; ++k) {
            half2v v;
            v[0] = (_Float16)w1row[2 * k];
            v[1] = (_Float16)w1row[2 * k + 1];
            w[k] = v;
        }
        bj = b1[tid];
    }

    // ---------------- consumer state ----------------
    float wz0 = 0, wz1 = 0, wz2 = 0, wz3 = 0;
    float w20 = 0, w21 = 0, w22 = 0, w23 = 0;
    if (is_consumer) {
        wz0 = W1[(lane +   0) * (DD + 1) + DD];
        wz1 = W1[(lane +  64) * (DD + 1) + DD];
        wz2 = W1[(lane + 128) * (DD + 1) + DD];
        wz3 = W1[(lane + 192) * (DD + 1) + DD];
        w20 = W2[lane +   0];
        w21 = W2[lane +  64];
        w22 = W2[lane + 128];
        w23 = W2[lane + 192];
    }
    const float b2s = b2[0];

    // stage x tile i (16 rows f32 -> f16 LDS); 256 producer threads
    auto stage_x = [&](int i) {
        const int r  = tid >> 4;           // 0..15
        const int c8 = (tid & 15) * 8;     // 0..120
        long long row = (long long)s0 + (long long)i * TILE + r;
        if (row > (long long)(T_TOTAL - 1)) row = T_TOTAL - 1;
        const float* src = X + row * DD + c8;
        float4 f0 = *(const float4*)(src);
        float4 f1 = *(const float4*)(src + 4);
        half2v* dst = &xs[i & 1][r][c8 >> 1];
        dst[0] = half2v{(_Float16)f0.x, (_Float16)f0.y};
        dst[1] = half2v{(_Float16)f0.z, (_Float16)f0.w};
        dst[2] = half2v{(_Float16)f1.x, (_Float16)f1.y};
        dst[3] = half2v{(_Float16)f1.z, (_Float16)f1.w};
    };

    // producers: compute A for tile i into As[i&1]
    auto produce = [&](int i) {
        #pragma unroll 2
        for (int s = 0; s < TILE; ++s) {
            const float4* xr4 = (const float4*)(&xs[i & 1][s][0]);
            float acc0 = 0.f, acc1 = 0.f, acc2 = 0.f, acc3 = 0.f;
            #pragma unroll
            for (int k4 = 0; k4 < DD / 8; ++k4) {        // 16 x ds_read_b128
                float4 xv = xr4[k4];
                acc0 = dot2f(w[4 * k4 + 0], __builtin_bit_cast(half2v, xv.x), acc0);
                acc1 = dot2f(w[4 * k4 + 1], __builtin_bit_cast(half2v, xv.y), acc1);
                acc2 = dot2f(w[4 * k4 + 2], __builtin_bit_cast(half2v, xv.z), acc2);
                acc3 = dot2f(w[4 * k4 + 3], __builtin_bit_cast(half2v, xv.w), acc3);
            }
            As[i & 1][s][tid] = ((acc0 + acc1) + (acc2 + acc3)) + bj;
        }
    };

    // ---------------- prologue ----------------
    if (!is_consumer) stage_x(0);
    __syncthreads();
    if (!is_consumer) { produce(0); stage_x(1); }
    __syncthreads();

    float z = 0.0f;

    for (int i = 0; i < ntiles; ++i) {
        if (!is_consumer) {
            if (i + 1 < ntiles) { produce(i + 1); stage_x(i + 2); }
        } else {
            const int   steps = min(TILE, nsteps - i * TILE);
            const int   tbase = s0 + 1 + i * TILE;
            const float* Abuf = &As[i & 1][0][0];
            if (steps == TILE) {
                #pragma unroll
                for (int s = 0; s < TILE; ++s) {
                    const float* Ar = Abuf + s * HH;
                    float h0 = fast_tanh(fmaf(wz0, z, Ar[lane]));
                    float h1 = fast_tanh(fmaf(wz1, z, Ar[lane + 64]));
                    float h2 = fast_tanh(fmaf(wz2, z, Ar[lane + 128]));
                    float h3 = fast_tanh(fmaf(wz3, z, Ar[lane + 192]));
                    float p = h0 * w20;
                    p = fmaf(h1, w21, p);
                    p = fmaf(h2, w22, p);
                    p = fmaf(h3, w23, p);
                    p = wave64_sum_lane63(p);
                    float u = __int_as_float(
                        __builtin_amdgcn_readlane(__float_as_int(p), 63)) + b2s;
                    z = fast_tanh(u);
                    const int t = tbase + s;
                    if (lane == 0 && t >= write_start) out[t] = z;
                }
            } else {
                for (int s = 0; s < steps; ++s) {
                    const float* Ar = Abuf + s * HH;
                    float h0 = fast_tanh(fmaf(wz0, z, Ar[lane]));
                    float h1 = fast_tanh(fmaf(wz1, z, Ar[lane + 64]));
                    float h2 = fast_tanh(fmaf(wz2, z, Ar[lane + 128]));
                    float h3 = fast_tanh(fmaf(wz3, z, Ar[lane + 192]));
                    float p = h0 * w20;
                    p = fmaf(h1, w21, p);
                    p = fmaf(h2, w22, p);
                    p = fmaf(h3, w23, p);
                    p = wave64_sum_lane63(p);
                    float u = __int_as_float(
                        __builtin_amdgcn_readlane(__float_as_int(p), 63)) + b2s;
                    z = fast_tanh(u);
                    const int t = tbase + s;
                    if (lane == 0 && t >= write_start) out[t] = z;
                }
            }
        }
        __syncthreads();
    }
}

extern "C" void kernel_launch(void* const* d_in, const int* in_sizes, int n_in,
                              void* d_out, int out_size, void* d_ws, size_t ws_size,
                              hipStream_t stream) {
    const float* X  = (const float*)d_in[0];
    const float* W1 = (const float*)d_in[1];
    const float* b1 = (const float*)d_in[2];
    const float* W2 = (const float*)d_in[3];
    const float* b2 = (const float*)d_in[4];
    float* out = (float*)d_out;
    (void)in_sizes; (void)n_in; (void)out_size; (void)d_ws; (void)ws_size;

    rec_kernel<<<CHUNKS, NTHREADS, 0, stream>>>(X, W1, b1, W2, b2, out);
}

// Round 3
// 122.365 us; speedup vs baseline: 3.1410x; 3.0985x over previous
//
#include <hip/hip_runtime.h>
#include <hip/hip_fp16.h>

#define T_TOTAL 262144
#define DD 128
#define HH 256

// ---- phase 1: coefficient GEMM ----
#define P1_BLOCKS 1024
#define TILE_T 16
#define TILES_PER_BLOCK (T_TOTAL / TILE_T / P1_BLOCKS)   // 16

// ---- phase 2: serial chain ----
#define P2_CHUNKS 1024
#define P2_L (T_TOTAL / P2_CHUNKS)   // 256
#define BURN 40

typedef _Float16 half8 __attribute__((ext_vector_type(8)));
typedef float f32x4 __attribute__((ext_vector_type(4)));

__device__ __forceinline__ float fast_tanh(float x) {
    float e = __expf(2.0f * x);
#if __has_builtin(__builtin_amdgcn_rcpf)
    float r = __builtin_amdgcn_rcpf(e + 1.0f);
#else
    float r = 1.0f / (e + 1.0f);
#endif
    return 1.0f - 2.0f * r;
}

template <int CTRL>
__device__ __forceinline__ float dpp_add(float x) {
    int t = __builtin_amdgcn_update_dpp(0, __float_as_int(x), CTRL, 0xf, 0xf, true);
    return x + __int_as_float(t);
}

// sum across the 16 lanes of each DPP row; lane (l&15)==15 holds the row sum
__device__ __forceinline__ float red16(float v) {
    v = dpp_add<0x111>(v);   // row_shr:1
    v = dpp_add<0x112>(v);   // row_shr:2
    v = dpp_add<0x114>(v);   // row_shr:4
    v = dpp_add<0x118>(v);   // row_shr:8
    return v;
}

__device__ __forceinline__ half8 cvt8(float4 a, float4 b) {
    half8 h;
    h[0] = (_Float16)a.x; h[1] = (_Float16)a.y;
    h[2] = (_Float16)a.z; h[3] = (_Float16)a.w;
    h[4] = (_Float16)b.x; h[5] = (_Float16)b.y;
    h[6] = (_Float16)b.z; h[7] = (_Float16)b.w;
    return h;
}

// Phase 1: for every step t compute cubic coefficients of
//   u(z) = sum_j W2_j * tanh(A[t][j] + wz_j * z) + b2
// via 3rd-order Taylor in eps = wz_j*z (|eps| <~ 0.25, remainder ~1e-5):
//   c0 = sum W2 f + b2 ; c1 = sum W2 wz d ; c2 = -sum W2 wz^2 f d ;
//   c3 = sum W2 wz^3 d (f^2 - 1/3)          with f = tanh(a), d = 1-f^2.
__global__ __launch_bounds__(256, 2)
void coeff_kernel(const float* __restrict__ X, const float* __restrict__ W1,
                  const float* __restrict__ b1, const float* __restrict__ W2,
                  const float* __restrict__ b2, float4* __restrict__ cs)
{
    const int tid = threadIdx.x;
    const int wid = tid >> 6;         // wave 0..3 owns j in [64w, 64w+64)
    const int l   = tid & 63;
    const int r16 = l & 15;           // fragment row/col index
    const int g   = l >> 4;           // k-group
    const int jb  = wid * 64;

    // ---- permanent W fragments: B[k][n] = W1[jb+js*16+n][k], js,ks in 0..3 ----
    half8 wf[4][4];
    float b1j[4], q0[4], q1[4], q2n[4], q3[4];
    #pragma unroll
    for (int js = 0; js < 4; ++js) {
        const int j = jb + js * 16 + r16;
        const float* wr = W1 + j * (DD + 1);
        #pragma unroll
        for (int ks = 0; ks < 4; ++ks) {
            const float4 a = *(const float4*)(wr + g * 8 + ks * 32);
            const float4 b = *(const float4*)(wr + g * 8 + ks * 32 + 4);
            wf[js][ks] = cvt8(a, b);
        }
        b1j[js] = b1[j];
        const float wz = wr[DD];
        const float w2 = W2[j];
        q0[js]  = w2;
        q1[js]  = w2 * wz;
        q2n[js] = -w2 * wz * wz;
        q3[js]  = w2 * wz * wz * wz;
    }
    const float b2s = b2[0];

    __shared__ float4 red[4][TILE_T];

    const int t0 = blockIdx.x * (TILES_PER_BLOCK * TILE_T);

    float4 xa[4][2];
    auto issue_loads = [&](int tt) {
        const float* xr = X + (long long)(tt + r16) * DD + g * 8;
        #pragma unroll
        for (int ks = 0; ks < 4; ++ks) {
            xa[ks][0] = *(const float4*)(xr + ks * 32);
            xa[ks][1] = *(const float4*)(xr + ks * 32 + 4);
        }
    };

    issue_loads(t0);

    for (int tile = 0; tile < TILES_PER_BLOCK; ++tile) {
        const int tt = t0 + tile * TILE_T;

        half8 xf[4];
        #pragma unroll
        for (int ks = 0; ks < 4; ++ks) xf[ks] = cvt8(xa[ks][0], xa[ks][1]);
        if (tile + 1 < TILES_PER_BLOCK) issue_loads(tt + TILE_T);   // prefetch

        f32x4 acc[4];
        #pragma unroll
        for (int js = 0; js < 4; ++js) acc[js] = f32x4{0.f, 0.f, 0.f, 0.f};
        #pragma unroll
        for (int js = 0; js < 4; ++js)
            #pragma unroll
            for (int ks = 0; ks < 4; ++ks)
                acc[js] = __builtin_amdgcn_mfma_f32_16x16x32_f16(
                    xf[ks], wf[js][ks], acc[js], 0, 0, 0);

        // ---- postproc: per element (t = tt + g*4 + r, j = jb + js*16 + r16) ----
        f32x4 c0 = {0,0,0,0}, c1 = {0,0,0,0}, c2 = {0,0,0,0}, c3 = {0,0,0,0};
        #pragma unroll
        for (int js = 0; js < 4; ++js) {
            #pragma unroll
            for (int r = 0; r < 4; ++r) {
                const float a  = acc[js][r] + b1j[js];
                const float f  = fast_tanh(a);
                const float ff = f * f;
                const float d  = 1.0f - ff;
                const float fd = f * d;
                const float t3 = d * (ff - 0.3333333333f);
                c0[r] = fmaf(q0[js],  f,  c0[r]);
                c1[r] = fmaf(q1[js],  d,  c1[r]);
                c2[r] = fmaf(q2n[js], fd, c2[r]);
                c3[r] = fmaf(q3[js],  t3, c3[r]);
            }
        }
        // reduce over the 16 j-lanes of each row
        #pragma unroll
        for (int r = 0; r < 4; ++r) {
            c0[r] = red16(c0[r]); c1[r] = red16(c1[r]);
            c2[r] = red16(c2[r]); c3[r] = red16(c3[r]);
        }
        if (r16 == 15) {
            #pragma unroll
            for (int r = 0; r < 4; ++r)
                red[wid][g * 4 + r] = make_float4(c0[r], c1[r], c2[r], c3[r]);
        }
        __syncthreads();
        if (tid < TILE_T) {
            const float4 a0 = red[0][tid], a1 = red[1][tid];
            const float4 a2 = red[2][tid], a3 = red[3][tid];
            float4 s;
            s.x = a0.x + a1.x + a2.x + a3.x + b2s;
            s.y = a0.y + a1.y + a2.y + a3.y;
            s.z = a0.z + a1.z + a2.z + a3.z;
            s.w = a0.w + a1.w + a2.w + a3.w;
            cs[tt + tid] = s;
        }
        __syncthreads();
    }
}

// Phase 2: per chunk, burn in then run the scalar cubic chain.
__global__ __launch_bounds__(64)
void chain_kernel(const float4* __restrict__ cs, float* __restrict__ out)
{
    const int c   = blockIdx.x;
    const int tid = threadIdx.x;
    const int s0     = (c == 0) ? 0 : c * P2_L - BURN;
    const int t_end  = min((c + 1) * P2_L, T_TOTAL - 1);
    const int n      = t_end - s0;
    const int wstart = c * P2_L;

    __shared__ float4 cl[P2_L + BURN];
    for (int i = tid; i < n; i += 64) cl[i] = cs[s0 + i];
    __syncthreads();

    if (c == 0 && tid == 0) out[0] = 0.0f;

    float z = 0.0f;
    #pragma unroll 4
    for (int i = 0; i < n; ++i) {
        const float4 k = cl[i];
        const float u = fmaf(fmaf(fmaf(k.w, z, k.z), z, k.y), z, k.x);
        z = fast_tanh(u);
        const int t = s0 + i;
        if (tid == 0 && t >= wstart) out[t + 1] = z;
    }
}

extern "C" void kernel_launch(void* const* d_in, const int* in_sizes, int n_in,
                              void* d_out, int out_size, void* d_ws, size_t ws_size,
                              hipStream_t stream) {
    const float* X  = (const float*)d_in[0];
    const float* W1 = (const float*)d_in[1];
    const float* b1 = (const float*)d_in[2];
    const float* W2 = (const float*)d_in[3];
    const float* b2 = (const float*)d_in[4];
    float* out = (float*)d_out;
    float4* cs = (float4*)d_ws;        // 262144 * 16 B = 4 MiB of scratch
    (void)in_sizes; (void)n_in; (void)out_size; (void)ws_size;

    coeff_kernel<<<P1_BLOCKS, 256, 0, stream>>>(X, W1, b1, W2, b2, cs);
    chain_kernel<<<P2_CHUNKS, 64, 0, stream>>>(cs, out);
}